// Round 6
// baseline (462.900 us; speedup 1.0000x reference)
//
#include <hip/hip_runtime.h>
#include <hip/hip_bf16.h>
#include <math.h>

#define B_ 4
#define S_ 2048
#define D_ 768
#define H_ 12
#define DH_ 64
#define F_ 3072
#define NTOK (B_*S_)   // 8192
#define BH_ (B_*H_)    // 48

typedef __hip_bfloat16 bf16;
typedef __attribute__((ext_vector_type(8))) short bf16x8;   // 8 bf16 = 4 VGPRs (MFMA A/B frag)
typedef __attribute__((ext_vector_type(4))) float f32x4;    // MFMA C/D frag
typedef __attribute__((ext_vector_type(4))) _Float16 half4;
typedef __attribute__((ext_vector_type(8))) _Float16 half8;

// async global->LDS: 16 B/lane, lane i lands at ldsbase + i*16 (wave-uniform base)
#define GLD16(g, l) __builtin_amdgcn_global_load_lds( \
    (__attribute__((address_space(1))) void*)(uintptr_t)(g), \
    (__attribute__((address_space(3))) void*)(uintptr_t)(l), 16, 0, 0)

__device__ __forceinline__ float bs2f(short s){
  union { unsigned int u; float f; } cv; cv.u = ((unsigned int)(unsigned short)s) << 16; return cv.f;
}
__device__ __forceinline__ float b2f(bf16 v){ return __bfloat162float(v); }
__device__ __forceinline__ bf16 f2b(float v){ return __float2bfloat16(v); }
__device__ __forceinline__ short f2bb(float v){ bf16 b = f2b(v); short s; __builtin_memcpy(&s, &b, 2); return s; }

// fast GELU (tanh form via v_exp_f32): max |err vs exact erf form| ~3e-3
__device__ __forceinline__ float gelu_fast(float v){
  float u  = v * (0.7978845608028654f + 0.035677408136f * v * v);
  float ay = fabsf(u);
  float t  = __expf(-2.0f * ay);
  float th = 1.0f - 2.0f * t / (1.0f + t);     // tanh(|u|)
  th = copysignf(th, u);
  return 0.5f * v * (1.0f + th);
}

// ---------------- fp32 -> bf16 convert ----------------
__global__ void f32_to_bf16_k(const float* __restrict__ in, bf16* __restrict__ out, int n){
  int i = blockIdx.x*256 + threadIdx.x;
  if (i < n) out[i] = f2b(in[i]);
}

// ------- transpose+convert: in[K][N] f32 -> out[N][K] bf16 (LDS 32x32 tiles) -------
__global__ __launch_bounds__(256) void transpose_f32_bf16_k(const float* __restrict__ in,
    bf16* __restrict__ out, int K, int N){
  __shared__ float t[32][33];
  const int kb = blockIdx.y*32, nb = blockIdx.x*32;
  const int x = threadIdx.x & 31, y = threadIdx.x >> 5;
#pragma unroll
  for (int yy = y; yy < 32; yy += 8)
    t[yy][x] = in[(size_t)(kb+yy)*N + nb + x];
  __syncthreads();
#pragma unroll
  for (int yy = y; yy < 32; yy += 8)
    out[(size_t)(nb+yy)*K + kb + x] = f2b(t[x][yy]);
}

// ---- pack Wq/Wk/Wv [H,D,Dh] -> WcatT [3D][D] (n-major, k contiguous), biases -> bcat[3D] ----
__global__ void pack_qkv_t_k(const float* __restrict__ Wq, const float* __restrict__ bq,
                             const float* __restrict__ Wk, const float* __restrict__ bk,
                             const float* __restrict__ Wv, const float* __restrict__ bv,
                             bf16* __restrict__ Wt, float* __restrict__ bcat){
  int idx = blockIdx.x*256 + threadIdx.x;
  if (idx < 3*D_*D_){
    int n = idx / D_;
    int k = idx - n*D_;
    int which = n / D_;
    int cc = n - which*D_;
    int h = cc >> 6, e = cc & 63;
    const float* W = (which==0) ? Wq : ((which==1) ? Wk : Wv);
    Wt[idx] = f2b(W[((size_t)h*D_ + k)*DH_ + e]);
  }
  if (idx < 3*D_){
    int which = idx / D_;
    int cc = idx - which*D_;
    int h = cc >> 6, e = cc & 63;
    const float* bb = (which==0) ? bq : ((which==1) ? bk : bv);
    bcat[idx] = bb[h*DH_ + e];
  }
}

// ---------------- MFMA GEMM: C[M,N] = A[M,K] @ Bt[N,K]^T  (+bias, epilogues) ----------------
// 128x128 tile, BK=32, 4 waves 2x2, global_load_lds width-16 staging.
// LDS chunk swizzle: slot c of row r holds global chunk c ^ ((r>>1)&3) -> 2-way bank aliasing (free).
// XCD-aware tile remap: the NX tiles sharing one A row-block get the same (flat%8) -> same XCD L2.
// EPI 0: +bias; q scaled 1/8 -> qb; k -> kb; v -> f16 vt[bh][e][s'] (key-permuted)
// EPI 1: +bias+aux residual -> bf16 C ;  EPI 2: +bias, fast GELU -> bf16 C
template<int EPI>
__global__ __launch_bounds__(256) void mgemm_k(
    const bf16* __restrict__ A, const bf16* __restrict__ Bt,
    const float* __restrict__ bias, const bf16* __restrict__ aux,
    bf16* __restrict__ C, int M, int N, int K,
    bf16* __restrict__ qb, bf16* __restrict__ kbuf, _Float16* __restrict__ vt)
{
  __shared__ bf16 As[4096];   // [128][32] unpadded, 8 KB
  __shared__ bf16 Bs[4096];
  const int tid  = threadIdx.x;
  const int wave = tid >> 6, lane = tid & 63;
  const int quad = lane >> 4, l16 = lane & 15;
  const int wm = (wave >> 1) * 64, wn = (wave & 1) * 64;

  // XCD-aware remap (requires gridDim.y % 8 == 0; true for all our launches)
  const int NX = gridDim.x;
  const int f  = blockIdx.y * NX + blockIdx.x;
  const int xcd = f & 7;
  const int j   = f >> 3;
  const int bx  = j % NX;
  const int by  = (j / NX) * 8 + xcd;
  const int m0 = by * 128, n0 = bx * 128;

  // staging: lane covers row wave*16 + (lane>>2), swizzled chunk ((lane&3)^((srow>>1)&3))
  const int srow  = lane >> 2;
  const int schunk = (lane & 3) ^ ((srow >> 1) & 3);
  const bf16* gA0 = A  + (size_t)(m0 + wave*16 + srow)*K + schunk*8;
  const bf16* gA1 = gA0 + (size_t)64*K;
  const bf16* gB0 = Bt + (size_t)(n0 + wave*16 + srow)*K + schunk*8;
  const bf16* gB1 = gB0 + (size_t)64*K;
  const uintptr_t asb = (uintptr_t)(void*)As + (size_t)wave*1024;
  const uintptr_t bsb = (uintptr_t)(void*)Bs + (size_t)wave*1024;

  f32x4 acc[4][4];
#pragma unroll
  for (int i=0;i<4;i++)
#pragma unroll
    for (int j2=0;j2<4;j2++) acc[i][j2] = (f32x4)0.f;

  const char* AsB = (const char*)As;
  const char* BsB = (const char*)Bs;
  const int fsw = (quad ^ ((l16 >> 1) & 3)) * 16;   // frag-read swizzled chunk byte offset

  for (int k0 = 0; k0 < K; k0 += 32){
    __syncthreads();                      // prior frag reads done before overwrite
    GLD16(gA0, asb);
    GLD16(gA1, asb + 4096);
    GLD16(gB0, bsb);
    GLD16(gB1, bsb + 4096);
    gA0 += 32; gA1 += 32; gB0 += 32; gB1 += 32;
    __syncthreads();                      // drains vmcnt -> LDS visible
    bf16x8 af[4], bfr[4];
#pragma unroll
    for (int i=0;i<4;i++) af[i]  = *(const bf16x8*)(AsB + ((wm + i*16 + l16) << 6) + fsw);
#pragma unroll
    for (int j2=0;j2<4;j2++) bfr[j2] = *(const bf16x8*)(BsB + ((wn + j2*16 + l16) << 6) + fsw);
#pragma unroll
    for (int i=0;i<4;i++)
#pragma unroll
      for (int j2=0;j2<4;j2++)
        acc[i][j2] = __builtin_amdgcn_mfma_f32_16x16x32_bf16(af[i], bfr[j2], acc[i][j2], 0, 0, 0);
  }

#pragma unroll
  for (int i=0;i<4;i++){
#pragma unroll
    for (int j2=0;j2<4;j2++){
      const int n = n0 + wn + j2*16 + l16;
      const int m_base = m0 + wm + i*16 + quad*4;
      if (EPI == 0){
        const int which = n / D_;
        const int cc = n - which*D_;
        const int h = cc >> 6, e = cc & 63;
        if (which == 2){
          const int b = m_base >> 11, s = m_base & (S_-1);
          const int sl = s & 63;
          const int perm = ((sl>>2)&3)*16 + ((sl>>4)&3)*4;   // key-permuted V^T layout
          half4 hv;
#pragma unroll
          for (int r=0;r<4;r++) hv[r] = (_Float16)(acc[i][j2][r] + bias[n]);
          *(half4*)(vt + ((size_t)(b*H_+h)*DH_ + e)*S_ + (s & ~63) + perm) = hv;
        } else {
          bf16* dst = (which==0) ? qb : kbuf;
          const float sc2 = (which==0) ? 0.125f : 1.0f;   // fold softmax 1/sqrt(64) into q
#pragma unroll
          for (int r=0;r<4;r++){
            const int m = m_base + r;
            const int b = m >> 11, s = m & (S_-1);
            dst[((size_t)(b*H_+h)*S_ + s)*DH_ + e] = f2b((acc[i][j2][r] + bias[n]) * sc2);
          }
        }
      } else {
#pragma unroll
        for (int r=0;r<4;r++){
          const int m = m_base + r;
          float v = acc[i][j2][r] + bias[n];
          if (EPI == 1){
            v += b2f(aux[(size_t)m*N + n]);
            C[(size_t)m*N + n] = f2b(v);
          } else {
            C[(size_t)m*N + n] = f2b(gelu_fast(v));
          }
        }
      }
    }
  }
}

// ---------------- MFMA flash attention ----------------
// Block: 64 queries, 4 waves in 2x2 (kh = key-half, qh = query-half).
// S^T = K@Q^T via 16x16x32_bf16; C layout: key=quad*4+r, query=l16.
// PV: O^T += V^T @ P^T via 16x16x16_f16 — S^T's C-frag IS the x16 B-frag, P stays in registers.
__global__ __launch_bounds__(256) void fattn_k(const bf16* __restrict__ qb,
    const bf16* __restrict__ kb, const _Float16* __restrict__ vt, bf16* __restrict__ ctx)
{
  __shared__ __align__(16) char smem[19456];
  bf16     (*Ks)[72] = (bf16(*)[72])smem;                  // [64 keys][72] bf16
  _Float16 (*Vs)[72] = (_Float16(*)[72])(smem + 9216);     // [64 d][72 keys(permuted)] f16
  float* maxb  = (float*)(smem + 18432);                   // [2 kh][64 q]
  float* libuf = (float*)(smem + 18944);                   // [2 kh][64 q]
  float* Obuf  = (float*)smem;                             // alias (end)

  const int bh = blockIdx.x;
  const int qt = 31 - blockIdx.y;       // heavy tiles first
  const int q0 = qt * 64;
  const int tid = threadIdx.x;
  const int wave = tid >> 6, lane = tid & 63;
  const int quad = lane >> 4, l16 = lane & 15;
  const int kh = wave >> 1, qh = wave & 1;
  const size_t kbase = (size_t)bh * S_ * DH_;

  bf16x8 qf[2][2];
#pragma unroll
  for (int nf=0; nf<2; nf++)
#pragma unroll
    for (int h=0; h<2; h++)
      qf[nf][h] = *(const bf16x8*)(qb + kbase + (size_t)(q0 + qh*32 + nf*16 + l16)*DH_ + h*32 + quad*8);

  f32x4 o[4][2];
#pragma unroll
  for (int df=0; df<4; df++){ o[df][0] = (f32x4)0.f; o[df][1] = (f32x4)0.f; }
  float mi[2] = {-1e30f, -1e30f}, li[2] = {0.f, 0.f};

  for (int kt = 0; kt <= qt; ++kt){
    const int k0 = kt * 64;
    __syncthreads();
    { // stage K (natural) and V^T (permuted keys)
      const int r = tid >> 2, seg = (tid & 3) * 16;
      const bf16* ksrc = kb + kbase + (size_t)(k0 + r)*DH_ + seg;
      bf16x8 ka = *(const bf16x8*)ksrc;
      bf16x8 kc2 = *(const bf16x8*)(ksrc + 8);
      *(bf16x8*)&Ks[r][seg]   = ka;
      *(bf16x8*)&Ks[r][seg+8] = kc2;
      const _Float16* vsrc = vt + ((size_t)bh*DH_ + r)*S_ + k0 + seg;
      half8 va = *(const half8*)vsrc;
      half8 vb2 = *(const half8*)(vsrc + 8);
      *(half8*)&Vs[r][seg]   = va;
      *(half8*)&Vs[r][seg+8] = vb2;
    }
    __syncthreads();

    bf16x8 af[2][2];
#pragma unroll
    for (int mf=0; mf<2; mf++)
#pragma unroll
      for (int h=0; h<2; h++)
        af[mf][h] = *(const bf16x8*)&Ks[kh*32 + mf*16 + l16][h*32 + quad*8];
    f32x4 sc[2][2];
#pragma unroll
    for (int mf=0; mf<2; mf++)
#pragma unroll
      for (int nf=0; nf<2; nf++){
        f32x4 t = __builtin_amdgcn_mfma_f32_16x16x32_bf16(af[mf][0], qf[nf][0], (f32x4)0.f, 0, 0, 0);
        sc[mf][nf] = __builtin_amdgcn_mfma_f32_16x16x32_bf16(af[mf][1], qf[nf][1], t, 0, 0, 0);
      }

    if (kt == qt){
#pragma unroll
      for (int mf=0; mf<2; mf++){
        const int keyl = kh*32 + mf*16 + quad*4;
#pragma unroll
        for (int nf=0; nf<2; nf++){
          const int ql = qh*32 + nf*16 + l16;
#pragma unroll
          for (int r=0; r<4; r++)
            if (keyl + r > ql) sc[mf][nf][r] = -1e30f;
        }
      }
    }

    float mw[2];
#pragma unroll
    for (int nf=0; nf<2; nf++){
      float mx = -1e30f;
#pragma unroll
      for (int mf=0; mf<2; mf++)
#pragma unroll
        for (int r=0; r<4; r++) mx = fmaxf(mx, sc[mf][nf][r]);
      mx = fmaxf(mx, __shfl_xor(mx, 16));
      mx = fmaxf(mx, __shfl_xor(mx, 32));
      mw[nf] = mx;
    }
    if (quad == 0){
      maxb[kh*64 + qh*32 + l16]      = mw[0];
      maxb[kh*64 + qh*32 + 16 + l16] = mw[1];
    }
    __syncthreads();

    half4 pf[2][2];
    float alpha[2];
#pragma unroll
    for (int nf=0; nf<2; nf++){
      const float mo = maxb[(1-kh)*64 + qh*32 + nf*16 + l16];
      const float mn = fmaxf(mi[nf], fmaxf(mw[nf], mo));
      alpha[nf] = __expf(mi[nf] - mn);
      mi[nf] = mn;
      float rs = 0.f;
#pragma unroll
      for (int mf=0; mf<2; mf++)
#pragma unroll
        for (int r=0; r<4; r++){
          float p = __expf(sc[mf][nf][r] - mn);
          pf[mf][nf][r] = (_Float16)p;
          rs += p;
        }
      rs += __shfl_xor(rs, 16);
      rs += __shfl_xor(rs, 32);
      li[nf] = li[nf]*alpha[nf] + rs;
    }

#pragma unroll
    for (int df=0; df<4; df++)
#pragma unroll
      for (int nf=0; nf<2; nf++)
#pragma unroll
        for (int r=0; r<4; r++) o[df][nf][r] *= alpha[nf];

#pragma unroll
    for (int df=0; df<4; df++){
      half8 vv = *(const half8*)&Vs[df*16 + l16][quad*16 + kh*8];
      half4 vlo = __builtin_shufflevector(vv, vv, 0,1,2,3);
      half4 vhi = __builtin_shufflevector(vv, vv, 4,5,6,7);
#pragma unroll
      for (int nf=0; nf<2; nf++){
        o[df][nf] = __builtin_amdgcn_mfma_f32_16x16x16f16(vlo, pf[0][nf], o[df][nf], 0, 0, 0);
        o[df][nf] = __builtin_amdgcn_mfma_f32_16x16x16f16(vhi, pf[1][nf], o[df][nf], 0, 0, 0);
      }
    }
  }

  __syncthreads();
  if (quad == 0){
    libuf[kh*64 + qh*32 + l16]      = li[0];
    libuf[kh*64 + qh*32 + 16 + l16] = li[1];
  }
  if (kh == 1){
#pragma unroll
    for (int df=0; df<4; df++)
#pragma unroll
      for (int nf=0; nf<2; nf++)
#pragma unroll
        for (int r=0; r<4; r++)
          Obuf[(qh*64 + df*16 + quad*4 + r)*33 + nf*16 + l16] = o[df][nf][r];
  }
  __syncthreads();
  if (kh == 0){
    const int b = bh / H_, h = bh - (bh / H_)*H_;
#pragma unroll
    for (int nf=0; nf<2; nf++){
      const int q64 = qh*32 + nf*16 + l16;
      const float inv = 1.0f / (libuf[q64] + libuf[64 + q64]);
      const int qtok = q0 + q64;
#pragma unroll
      for (int df=0; df<4; df++){
        short4 pk;
        float v0 = (o[df][nf][0] + Obuf[(qh*64 + df*16 + quad*4 + 0)*33 + nf*16 + l16]) * inv;
        float v1 = (o[df][nf][1] + Obuf[(qh*64 + df*16 + quad*4 + 1)*33 + nf*16 + l16]) * inv;
        float v2 = (o[df][nf][2] + Obuf[(qh*64 + df*16 + quad*4 + 2)*33 + nf*16 + l16]) * inv;
        float v3 = (o[df][nf][3] + Obuf[(qh*64 + df*16 + quad*4 + 3)*33 + nf*16 + l16]) * inv;
        pk.x = f2bb(v0); pk.y = f2bb(v1); pk.z = f2bb(v2); pk.w = f2bb(v3);
        *(short4*)((short*)ctx + ((size_t)(b*S_ + qtok))*D_ + h*DH_ + df*16 + quad*4) = pk;
      }
    }
  }
}

// ---------------- layernorm over D=768 ----------------
template<typename T> __device__ __forceinline__ void stf(T* p, float v);
template<> __device__ __forceinline__ void stf<float>(float* p, float v){ *p = v; }
template<> __device__ __forceinline__ void stf<bf16>(bf16* p, float v){ *p = f2b(v); }

template<typename OutT>
__global__ __launch_bounds__(256) void layernorm_k(const bf16* __restrict__ X,
    const float* __restrict__ g, const float* __restrict__ bta, OutT* __restrict__ Y)
{
  const int row = blockIdx.x;
  const int tid = threadIdx.x;
  const bf16* xr = X + (size_t)row * D_;
  float vals[3];
  float s = 0.f, s2 = 0.f;
#pragma unroll
  for (int i = 0; i < 3; i++){
    float v = b2f(xr[tid + i*256]);
    vals[i] = v; s += v; s2 += v*v;
  }
#pragma unroll
  for (int o = 32; o > 0; o >>= 1){ s += __shfl_down(s, o); s2 += __shfl_down(s2, o); }
  __shared__ float rs[4], rq[4];
  const int lane = tid & 63, w = tid >> 6;
  if (lane == 0){ rs[w] = s; rq[w] = s2; }
  __syncthreads();
  s  = rs[0]+rs[1]+rs[2]+rs[3];
  s2 = rq[0]+rq[1]+rq[2]+rq[3];
  const float mean = s * (1.0f/D_);
  const float var  = s2 * (1.0f/D_) - mean*mean;
  const float inv  = rsqrtf(var + 1e-5f);
#pragma unroll
  for (int i = 0; i < 3; i++){
    int c = tid + i*256;
    float o = (vals[i] - mean) * inv * g[c] + bta[c];
    stf(Y + (size_t)row*D_ + c, o);
  }
}

extern "C" void kernel_launch(void* const* d_in, const int* in_sizes, int n_in,
                              void* d_out, int out_size, void* d_ws, size_t ws_size,
                              hipStream_t stream)
{
  const float* x   = (const float*)d_in[0];
  const float* Wq  = (const float*)d_in[1];
  const float* bq  = (const float*)d_in[2];
  const float* Wk  = (const float*)d_in[3];
  const float* bk  = (const float*)d_in[4];
  const float* Wv  = (const float*)d_in[5];
  const float* bv  = (const float*)d_in[6];
  const float* Wo  = (const float*)d_in[7];
  const float* bo  = (const float*)d_in[8];
  const float* W1  = (const float*)d_in[9];
  const float* b1  = (const float*)d_in[10];
  const float* W2  = (const float*)d_in[11];
  const float* b2  = (const float*)d_in[12];
  const float* g1  = (const float*)d_in[13];
  const float* be1 = (const float*)d_in[14];
  const float* g2  = (const float*)d_in[15];
  const float* be2 = (const float*)d_in[16];
  float* out = (float*)d_out;

  char* ws = (char*)d_ws;
  size_t off = 0;
  auto alloc = [&](size_t bytes)->char*{
    char* p = ws + off; off = (off + bytes + 255) & ~(size_t)255; return p;
  };
  bf16*  xb    = (bf16*) alloc((size_t)NTOK*D_*2);
  bf16*  WcatT = (bf16*) alloc((size_t)3*D_*D_*2);
  float* bcat  = (float*)alloc((size_t)3*D_*4);
  bf16*  WoT   = (bf16*) alloc((size_t)D_*D_*2);
  bf16*  W1T   = (bf16*) alloc((size_t)F_*D_*2);
  bf16*  W2T   = (bf16*) alloc((size_t)D_*F_*2);
  bf16*  r1    = (bf16*) alloc((size_t)NTOK*F_*2);     // q,k,vt then ff1
  bf16*  qb    = r1;
  bf16*  kb    = r1 + (size_t)NTOK*D_;
  _Float16* vt = (_Float16*)(r1 + (size_t)2*NTOK*D_);  // [bh*64+d][S], f16, key-permuted
  bf16*  ff1   = r1;
  bf16*  ctxb  = (bf16*) alloc((size_t)NTOK*D_*2);     // ctx then y2
  bf16*  y1    = (bf16*) alloc((size_t)NTOK*D_*2);
  bf16*  hb    = (bf16*) alloc((size_t)NTOK*D_*2);
  bf16*  y2    = ctxb;

  f32_to_bf16_k<<<(NTOK*D_+255)/256, 256, 0, stream>>>(x, xb, NTOK*D_);
  transpose_f32_bf16_k<<<dim3(D_/32, D_/32), 256, 0, stream>>>(Wo, WoT, D_, D_);
  transpose_f32_bf16_k<<<dim3(F_/32, D_/32), 256, 0, stream>>>(W1, W1T, D_, F_);
  transpose_f32_bf16_k<<<dim3(D_/32, F_/32), 256, 0, stream>>>(W2, W2T, F_, D_);
  pack_qkv_t_k<<<(3*D_*D_+255)/256, 256, 0, stream>>>(Wq,bq,Wk,bk,Wv,bv,WcatT,bcat);

  // 1) fused QKV projection (q pre-scaled 1/8; v written transposed+permuted f16)
  mgemm_k<0><<<dim3(3*D_/128, NTOK/128), 256, 0, stream>>>(
      xb, WcatT, bcat, nullptr, nullptr, NTOK, 3*D_, D_, qb, kb, vt);

  // 2) MFMA flash attention -> ctx [8192,768]
  fattn_k<<<dim3(BH_, S_/64), 256, 0, stream>>>(qb, kb, vt, ctxb);

  // 3) out-proj + residual: y1 = ctx@Wo + bo + x
  mgemm_k<1><<<dim3(D_/128, NTOK/128), 256, 0, stream>>>(
      ctxb, WoT, bo, xb, y1, NTOK, D_, D_, nullptr, nullptr, nullptr);

  // 4) LN1 -> h
  layernorm_k<bf16><<<NTOK, 256, 0, stream>>>(y1, g1, be1, hb);

  // 5) FF1 + fast GELU
  mgemm_k<2><<<dim3(F_/128, NTOK/128), 256, 0, stream>>>(
      hb, W1T, b1, nullptr, ff1, NTOK, F_, D_, nullptr, nullptr, nullptr);

  // 6) FF2 + residual: y2 = ff1@W2 + b2 + h
  mgemm_k<1><<<dim3(D_/128, NTOK/128), 256, 0, stream>>>(
      ff1, W2T, b2, hb, y2, NTOK, D_, F_, nullptr, nullptr, nullptr);

  // 7) LN2 -> out (fp32)
  layernorm_k<float><<<NTOK, 256, 0, stream>>>(y2, g2, be2, out);
}

// Round 7
// 422.573 us; speedup vs baseline: 1.0954x; 1.0954x over previous
//
#include <hip/hip_runtime.h>
#include <hip/hip_bf16.h>
#include <math.h>

#define B_ 4
#define S_ 2048
#define D_ 768
#define H_ 12
#define DH_ 64
#define F_ 3072
#define NTOK (B_*S_)   // 8192
#define BH_ (B_*H_)    // 48

typedef __hip_bfloat16 bf16;
typedef __attribute__((ext_vector_type(8))) short bf16x8;   // 8 bf16 = 4 VGPRs (MFMA A/B frag)
typedef __attribute__((ext_vector_type(4))) float f32x4;    // MFMA C/D frag
typedef __attribute__((ext_vector_type(4))) _Float16 half4;
typedef __attribute__((ext_vector_type(8))) _Float16 half8;

// async global->LDS: 16 B/lane, lane i lands at ldsbase + i*16 (wave-uniform base)
#define GLD16(g, l) __builtin_amdgcn_global_load_lds( \
    (__attribute__((address_space(1))) void*)(uintptr_t)(g), \
    (__attribute__((address_space(3))) void*)(uintptr_t)(l), 16, 0, 0)

__device__ __forceinline__ float bs2f(short s){
  union { unsigned int u; float f; } cv; cv.u = ((unsigned int)(unsigned short)s) << 16; return cv.f;
}
__device__ __forceinline__ float b2f(bf16 v){ return __bfloat162float(v); }
__device__ __forceinline__ bf16 f2b(float v){ return __float2bfloat16(v); }
__device__ __forceinline__ short f2bb(float v){ bf16 b = f2b(v); short s; __builtin_memcpy(&s, &b, 2); return s; }

// tanh-form GELU, algebraically rewritten: 0.5x(1+tanh(u)) = x * sigmoid(2u)
//   = x * rcp(1 + exp2(x*(c0 + c1*x^2))),  c = -2*log2(e)*{0.79788456, 0.03567741}
// 7 VALU insts (2 quarter-rate), same function as the tanh approximation.
__device__ __forceinline__ float gelu_fast(float v){
  const float c0 = -2.302208157f;
  const float c1 = -0.102943238f;
  float w = v*v;
  float z = v * __builtin_fmaf(c1, w, c0);
  float t = __builtin_amdgcn_exp2f(z);
  return v * __builtin_amdgcn_rcpf(1.0f + t);
}

// ---------------- fp32 -> bf16 convert ----------------
__global__ void f32_to_bf16_k(const float* __restrict__ in, bf16* __restrict__ out, int n){
  int i = blockIdx.x*256 + threadIdx.x;
  if (i < n) out[i] = f2b(in[i]);
}

// ------- transpose+convert: in[K][N] f32 -> out[N][K] bf16 (LDS 32x32 tiles) -------
__global__ __launch_bounds__(256) void transpose_f32_bf16_k(const float* __restrict__ in,
    bf16* __restrict__ out, int K, int N){
  __shared__ float t[32][33];
  const int kb = blockIdx.y*32, nb = blockIdx.x*32;
  const int x = threadIdx.x & 31, y = threadIdx.x >> 5;
#pragma unroll
  for (int yy = y; yy < 32; yy += 8)
    t[yy][x] = in[(size_t)(kb+yy)*N + nb + x];
  __syncthreads();
#pragma unroll
  for (int yy = y; yy < 32; yy += 8)
    out[(size_t)(nb+yy)*K + kb + x] = f2b(t[x][yy]);
}

// ---- pack Wq/Wk/Wv [H,D,Dh] -> WcatT [3D][D] (n-major, k contiguous), biases -> bcat[3D] ----
__global__ void pack_qkv_t_k(const float* __restrict__ Wq, const float* __restrict__ bq,
                             const float* __restrict__ Wk, const float* __restrict__ bk,
                             const float* __restrict__ Wv, const float* __restrict__ bv,
                             bf16* __restrict__ Wt, float* __restrict__ bcat){
  int idx = blockIdx.x*256 + threadIdx.x;
  if (idx < 3*D_*D_){
    int n = idx / D_;
    int k = idx - n*D_;
    int which = n / D_;
    int cc = n - which*D_;
    int h = cc >> 6, e = cc & 63;
    const float* W = (which==0) ? Wq : ((which==1) ? Wk : Wv);
    Wt[idx] = f2b(W[((size_t)h*D_ + k)*DH_ + e]);
  }
  if (idx < 3*D_){
    int which = idx / D_;
    int cc = idx - which*D_;
    int h = cc >> 6, e = cc & 63;
    const float* bb = (which==0) ? bq : ((which==1) ? bk : bv);
    bcat[idx] = bb[h*DH_ + e];
  }
}

// ---------------- MFMA GEMM 128x128: C[M,N] = A[M,K] @ Bt[N,K]^T ----------------
// BK=32, 4 waves 2x2, global_load_lds width-16 staging, 2-way-only LDS swizzle,
// XCD-aware tile remap. EPI 0: qkv scatter; EPI 2: +bias, fast GELU -> bf16 C
template<int EPI>
__global__ __launch_bounds__(256) void mgemm_k(
    const bf16* __restrict__ A, const bf16* __restrict__ Bt,
    const float* __restrict__ bias, const bf16* __restrict__ aux,
    bf16* __restrict__ C, int M, int N, int K,
    bf16* __restrict__ qb, bf16* __restrict__ kbuf, _Float16* __restrict__ vt)
{
  __shared__ bf16 As[4096];   // [128][32] unpadded, 8 KB
  __shared__ bf16 Bs[4096];
  const int tid  = threadIdx.x;
  const int wave = tid >> 6, lane = tid & 63;
  const int quad = lane >> 4, l16 = lane & 15;
  const int wm = (wave >> 1) * 64, wn = (wave & 1) * 64;

  // XCD-aware remap (gridDim.y % 8 == 0 for all our launches)
  const int NX = gridDim.x;
  const int f  = blockIdx.y * NX + blockIdx.x;
  const int xcd = f & 7;
  const int j   = f >> 3;
  const int bx  = j % NX;
  const int by  = (j / NX) * 8 + xcd;
  const int m0 = by * 128, n0 = bx * 128;

  // staging: lane covers row wave*16 + (lane>>2), swizzled chunk ((lane&3)^((srow>>1)&3))
  const int srow  = lane >> 2;
  const int schunk = (lane & 3) ^ ((srow >> 1) & 3);
  const bf16* gA0 = A  + (size_t)(m0 + wave*16 + srow)*K + schunk*8;
  const bf16* gA1 = gA0 + (size_t)64*K;
  const bf16* gB0 = Bt + (size_t)(n0 + wave*16 + srow)*K + schunk*8;
  const bf16* gB1 = gB0 + (size_t)64*K;
  const uintptr_t asb = (uintptr_t)(void*)As + (size_t)wave*1024;
  const uintptr_t bsb = (uintptr_t)(void*)Bs + (size_t)wave*1024;

  f32x4 acc[4][4];
#pragma unroll
  for (int i=0;i<4;i++)
#pragma unroll
    for (int j2=0;j2<4;j2++) acc[i][j2] = (f32x4)0.f;

  const char* AsB = (const char*)As;
  const char* BsB = (const char*)Bs;
  const int fsw = (quad ^ ((l16 >> 1) & 3)) * 16;   // frag-read swizzled chunk byte offset

  for (int k0 = 0; k0 < K; k0 += 32){
    __syncthreads();                      // prior frag reads done before overwrite
    GLD16(gA0, asb);
    GLD16(gA1, asb + 4096);
    GLD16(gB0, bsb);
    GLD16(gB1, bsb + 4096);
    gA0 += 32; gA1 += 32; gB0 += 32; gB1 += 32;
    __syncthreads();                      // drains vmcnt -> LDS visible
    bf16x8 af[4], bfr[4];
#pragma unroll
    for (int i=0;i<4;i++) af[i]  = *(const bf16x8*)(AsB + ((wm + i*16 + l16) << 6) + fsw);
#pragma unroll
    for (int j2=0;j2<4;j2++) bfr[j2] = *(const bf16x8*)(BsB + ((wn + j2*16 + l16) << 6) + fsw);
#pragma unroll
    for (int i=0;i<4;i++)
#pragma unroll
      for (int j2=0;j2<4;j2++)
        acc[i][j2] = __builtin_amdgcn_mfma_f32_16x16x32_bf16(af[i], bfr[j2], acc[i][j2], 0, 0, 0);
  }

#pragma unroll
  for (int i=0;i<4;i++){
#pragma unroll
    for (int j2=0;j2<4;j2++){
      const int n = n0 + wn + j2*16 + l16;
      const int m_base = m0 + wm + i*16 + quad*4;
      if (EPI == 0){
        const int which = n / D_;
        const int cc = n - which*D_;
        const int h = cc >> 6, e = cc & 63;
        if (which == 2){
          const int b = m_base >> 11, s = m_base & (S_-1);
          const int sl = s & 63;
          const int perm = ((sl>>2)&3)*16 + ((sl>>4)&3)*4;   // key-permuted V^T layout
          half4 hv;
#pragma unroll
          for (int r=0;r<4;r++) hv[r] = (_Float16)(acc[i][j2][r] + bias[n]);
          *(half4*)(vt + ((size_t)(b*H_+h)*DH_ + e)*S_ + (s & ~63) + perm) = hv;
        } else {
          bf16* dst = (which==0) ? qb : kbuf;
          const float sc2 = (which==0) ? 0.125f : 1.0f;   // fold softmax 1/sqrt(64) into q
#pragma unroll
          for (int r=0;r<4;r++){
            const int m = m_base + r;
            const int b = m >> 11, s = m & (S_-1);
            dst[((size_t)(b*H_+h)*S_ + s)*DH_ + e] = f2b((acc[i][j2][r] + bias[n]) * sc2);
          }
        }
      } else {
#pragma unroll
        for (int r=0;r<4;r++){
          const int m = m_base + r;
          float v = acc[i][j2][r] + bias[n];
          if (EPI == 1){
            v += b2f(aux[(size_t)m*N + n]);
            C[(size_t)m*N + n] = f2b(v);
          } else {
            C[(size_t)m*N + n] = f2b(gelu_fast(v));
          }
        }
      }
    }
  }
}

// ---------------- MFMA GEMM 64x128 (for N=768 GEMMs: proj, FF2) ----------------
// TM=64, TN=128, BK=32; grid (N/128, M/64) -> 768 blocks = 3/CU. EPI1 only:
// C = A@Bt^T + bias + aux (residual), bf16 out. Same swizzle algebra as mgemm_k.
__global__ __launch_bounds__(256) void mgemm64_k(
    const bf16* __restrict__ A, const bf16* __restrict__ Bt,
    const float* __restrict__ bias, const bf16* __restrict__ aux,
    bf16* __restrict__ C, int M, int N, int K)
{
  __shared__ bf16 As[2048];   // [64][32]
  __shared__ bf16 Bs[4096];   // [128][32]
  const int tid  = threadIdx.x;
  const int wave = tid >> 6, lane = tid & 63;
  const int quad = lane >> 4, l16 = lane & 15;
  const int wm = (wave >> 1) * 32, wn = (wave & 1) * 64;

  const int NX = gridDim.x;
  const int f  = blockIdx.y * NX + blockIdx.x;
  const int xcd = f & 7;
  const int j   = f >> 3;
  const int bx  = j % NX;
  const int by  = (j / NX) * 8 + xcd;
  const int m0 = by * 64, n0 = bx * 128;

  const int srow  = lane >> 2;
  const int schunk = (lane & 3) ^ ((srow >> 1) & 3);
  // wave w stages A rows w*16..+15 (1 GLD) and B rows w*32..+31 (2 GLDs)
  const bf16* gA  = A  + (size_t)(m0 + wave*16 + srow)*K + schunk*8;
  const bf16* gB0 = Bt + (size_t)(n0 + wave*32 + srow)*K + schunk*8;
  const bf16* gB1 = gB0 + (size_t)16*K;
  const uintptr_t asb = (uintptr_t)(void*)As + (size_t)wave*1024;
  const uintptr_t bsb = (uintptr_t)(void*)Bs + (size_t)wave*2048;

  f32x4 acc[2][4];
#pragma unroll
  for (int i=0;i<2;i++)
#pragma unroll
    for (int j2=0;j2<4;j2++) acc[i][j2] = (f32x4)0.f;

  const char* AsB = (const char*)As;
  const char* BsB = (const char*)Bs;
  const int fsw = (quad ^ ((l16 >> 1) & 3)) * 16;

  for (int k0 = 0; k0 < K; k0 += 32){
    __syncthreads();
    GLD16(gA,  asb);
    GLD16(gB0, bsb);
    GLD16(gB1, bsb + 1024);
    gA += 32; gB0 += 32; gB1 += 32;
    __syncthreads();
    bf16x8 af[2], bfr[4];
#pragma unroll
    for (int i=0;i<2;i++) af[i]  = *(const bf16x8*)(AsB + ((wm + i*16 + l16) << 6) + fsw);
#pragma unroll
    for (int j2=0;j2<4;j2++) bfr[j2] = *(const bf16x8*)(BsB + ((wn + j2*16 + l16) << 6) + fsw);
#pragma unroll
    for (int i=0;i<2;i++)
#pragma unroll
      for (int j2=0;j2<4;j2++)
        acc[i][j2] = __builtin_amdgcn_mfma_f32_16x16x32_bf16(af[i], bfr[j2], acc[i][j2], 0, 0, 0);
  }

#pragma unroll
  for (int i=0;i<2;i++){
#pragma unroll
    for (int j2=0;j2<4;j2++){
      const int n = n0 + wn + j2*16 + l16;
      const int m_base = m0 + wm + i*16 + quad*4;
#pragma unroll
      for (int r=0;r<4;r++){
        const int m = m_base + r;
        float v = acc[i][j2][r] + bias[n] + b2f(aux[(size_t)m*N + n]);
        C[(size_t)m*N + n] = f2b(v);
      }
    }
  }
}

// ---------------- MFMA flash attention ----------------
__global__ __launch_bounds__(256) void fattn_k(const bf16* __restrict__ qb,
    const bf16* __restrict__ kb, const _Float16* __restrict__ vt, bf16* __restrict__ ctx)
{
  __shared__ __align__(16) char smem[19456];
  bf16     (*Ks)[72] = (bf16(*)[72])smem;                  // [64 keys][72] bf16
  _Float16 (*Vs)[72] = (_Float16(*)[72])(smem + 9216);     // [64 d][72 keys(permuted)] f16
  float* maxb  = (float*)(smem + 18432);                   // [2 kh][64 q]
  float* libuf = (float*)(smem + 18944);                   // [2 kh][64 q]
  float* Obuf  = (float*)smem;                             // alias (end)

  const int bh = blockIdx.x;
  const int qt = 31 - blockIdx.y;       // heavy tiles first
  const int q0 = qt * 64;
  const int tid = threadIdx.x;
  const int wave = tid >> 6, lane = tid & 63;
  const int quad = lane >> 4, l16 = lane & 15;
  const int kh = wave >> 1, qh = wave & 1;
  const size_t kbase = (size_t)bh * S_ * DH_;

  bf16x8 qf[2][2];
#pragma unroll
  for (int nf=0; nf<2; nf++)
#pragma unroll
    for (int h=0; h<2; h++)
      qf[nf][h] = *(const bf16x8*)(qb + kbase + (size_t)(q0 + qh*32 + nf*16 + l16)*DH_ + h*32 + quad*8);

  f32x4 o[4][2];
#pragma unroll
  for (int df=0; df<4; df++){ o[df][0] = (f32x4)0.f; o[df][1] = (f32x4)0.f; }
  float mi[2] = {-1e30f, -1e30f}, li[2] = {0.f, 0.f};

  for (int kt = 0; kt <= qt; ++kt){
    const int k0 = kt * 64;
    __syncthreads();
    { // stage K (natural) and V^T (permuted keys)
      const int r = tid >> 2, seg = (tid & 3) * 16;
      const bf16* ksrc = kb + kbase + (size_t)(k0 + r)*DH_ + seg;
      bf16x8 ka = *(const bf16x8*)ksrc;
      bf16x8 kc2 = *(const bf16x8*)(ksrc + 8);
      *(bf16x8*)&Ks[r][seg]   = ka;
      *(bf16x8*)&Ks[r][seg+8] = kc2;
      const _Float16* vsrc = vt + ((size_t)bh*DH_ + r)*S_ + k0 + seg;
      half8 va = *(const half8*)vsrc;
      half8 vb2 = *(const half8*)(vsrc + 8);
      *(half8*)&Vs[r][seg]   = va;
      *(half8*)&Vs[r][seg+8] = vb2;
    }
    __syncthreads();

    bf16x8 af[2][2];
#pragma unroll
    for (int mf=0; mf<2; mf++)
#pragma unroll
      for (int h=0; h<2; h++)
        af[mf][h] = *(const bf16x8*)&Ks[kh*32 + mf*16 + l16][h*32 + quad*8];
    f32x4 sc[2][2];
#pragma unroll
    for (int mf=0; mf<2; mf++)
#pragma unroll
      for (int nf=0; nf<2; nf++){
        f32x4 t = __builtin_amdgcn_mfma_f32_16x16x32_bf16(af[mf][0], qf[nf][0], (f32x4)0.f, 0, 0, 0);
        sc[mf][nf] = __builtin_amdgcn_mfma_f32_16x16x32_bf16(af[mf][1], qf[nf][1], t, 0, 0, 0);
      }

    if (kt == qt){
#pragma unroll
      for (int mf=0; mf<2; mf++){
        const int keyl = kh*32 + mf*16 + quad*4;
#pragma unroll
        for (int nf=0; nf<2; nf++){
          const int ql = qh*32 + nf*16 + l16;
#pragma unroll
          for (int r=0; r<4; r++)
            if (keyl + r > ql) sc[mf][nf][r] = -1e30f;
        }
      }
    }

    float mw[2];
#pragma unroll
    for (int nf=0; nf<2; nf++){
      float mx = -1e30f;
#pragma unroll
      for (int mf=0; mf<2; mf++)
#pragma unroll
        for (int r=0; r<4; r++) mx = fmaxf(mx, sc[mf][nf][r]);
      mx = fmaxf(mx, __shfl_xor(mx, 16));
      mx = fmaxf(mx, __shfl_xor(mx, 32));
      mw[nf] = mx;
    }
    if (quad == 0){
      maxb[kh*64 + qh*32 + l16]      = mw[0];
      maxb[kh*64 + qh*32 + 16 + l16] = mw[1];
    }
    __syncthreads();

    half4 pf[2][2];
    float alpha[2];
#pragma unroll
    for (int nf=0; nf<2; nf++){
      const float mo = maxb[(1-kh)*64 + qh*32 + nf*16 + l16];
      const float mn = fmaxf(mi[nf], fmaxf(mw[nf], mo));
      alpha[nf] = __expf(mi[nf] - mn);
      mi[nf] = mn;
      float rs = 0.f;
#pragma unroll
      for (int mf=0; mf<2; mf++)
#pragma unroll
        for (int r=0; r<4; r++){
          float p = __expf(sc[mf][nf][r] - mn);
          pf[mf][nf][r] = (_Float16)p;
          rs += p;
        }
      rs += __shfl_xor(rs, 16);
      rs += __shfl_xor(rs, 32);
      li[nf] = li[nf]*alpha[nf] + rs;
    }

#pragma unroll
    for (int df=0; df<4; df++)
#pragma unroll
      for (int nf=0; nf<2; nf++)
#pragma unroll
        for (int r=0; r<4; r++) o[df][nf][r] *= alpha[nf];

#pragma unroll
    for (int df=0; df<4; df++){
      half8 vv = *(const half8*)&Vs[df*16 + l16][quad*16 + kh*8];
      half4 vlo = __builtin_shufflevector(vv, vv, 0,1,2,3);
      half4 vhi = __builtin_shufflevector(vv, vv, 4,5,6,7);
#pragma unroll
      for (int nf=0; nf<2; nf++){
        o[df][nf] = __builtin_amdgcn_mfma_f32_16x16x16f16(vlo, pf[0][nf], o[df][nf], 0, 0, 0);
        o[df][nf] = __builtin_amdgcn_mfma_f32_16x16x16f16(vhi, pf[1][nf], o[df][nf], 0, 0, 0);
      }
    }
  }

  __syncthreads();
  if (quad == 0){
    libuf[kh*64 + qh*32 + l16]      = li[0];
    libuf[kh*64 + qh*32 + 16 + l16] = li[1];
  }
  if (kh == 1){
#pragma unroll
    for (int df=0; df<4; df++)
#pragma unroll
      for (int nf=0; nf<2; nf++)
#pragma unroll
        for (int r=0; r<4; r++)
          Obuf[(qh*64 + df*16 + quad*4 + r)*33 + nf*16 + l16] = o[df][nf][r];
  }
  __syncthreads();
  if (kh == 0){
    const int b = bh / H_, h = bh - (bh / H_)*H_;
#pragma unroll
    for (int nf=0; nf<2; nf++){
      const int q64 = qh*32 + nf*16 + l16;
      const float inv = 1.0f / (libuf[q64] + libuf[64 + q64]);
      const int qtok = q0 + q64;
#pragma unroll
      for (int df=0; df<4; df++){
        short4 pk;
        float v0 = (o[df][nf][0] + Obuf[(qh*64 + df*16 + quad*4 + 0)*33 + nf*16 + l16]) * inv;
        float v1 = (o[df][nf][1] + Obuf[(qh*64 + df*16 + quad*4 + 1)*33 + nf*16 + l16]) * inv;
        float v2 = (o[df][nf][2] + Obuf[(qh*64 + df*16 + quad*4 + 2)*33 + nf*16 + l16]) * inv;
        float v3 = (o[df][nf][3] + Obuf[(qh*64 + df*16 + quad*4 + 3)*33 + nf*16 + l16]) * inv;
        pk.x = f2bb(v0); pk.y = f2bb(v1); pk.z = f2bb(v2); pk.w = f2bb(v3);
        *(short4*)((short*)ctx + ((size_t)(b*S_ + qtok))*D_ + h*DH_ + df*16 + quad*4) = pk;
      }
    }
  }
}

// ---------------- layernorm over D=768 ----------------
template<typename T> __device__ __forceinline__ void stf(T* p, float v);
template<> __device__ __forceinline__ void stf<float>(float* p, float v){ *p = v; }
template<> __device__ __forceinline__ void stf<bf16>(bf16* p, float v){ *p = f2b(v); }

template<typename OutT>
__global__ __launch_bounds__(256) void layernorm_k(const bf16* __restrict__ X,
    const float* __restrict__ g, const float* __restrict__ bta, OutT* __restrict__ Y)
{
  const int row = blockIdx.x;
  const int tid = threadIdx.x;
  const bf16* xr = X + (size_t)row * D_;
  float vals[3];
  float s = 0.f, s2 = 0.f;
#pragma unroll
  for (int i = 0; i < 3; i++){
    float v = b2f(xr[tid + i*256]);
    vals[i] = v; s += v; s2 += v*v;
  }
#pragma unroll
  for (int o = 32; o > 0; o >>= 1){ s += __shfl_down(s, o); s2 += __shfl_down(s2, o); }
  __shared__ float rs[4], rq[4];
  const int lane = tid & 63, w = tid >> 6;
  if (lane == 0){ rs[w] = s; rq[w] = s2; }
  __syncthreads();
  s  = rs[0]+rs[1]+rs[2]+rs[3];
  s2 = rq[0]+rq[1]+rq[2]+rq[3];
  const float mean = s * (1.0f/D_);
  const float var  = s2 * (1.0f/D_) - mean*mean;
  const float inv  = rsqrtf(var + 1e-5f);
#pragma unroll
  for (int i = 0; i < 3; i++){
    int c = tid + i*256;
    float o = (vals[i] - mean) * inv * g[c] + bta[c];
    stf(Y + (size_t)row*D_ + c, o);
  }
}

extern "C" void kernel_launch(void* const* d_in, const int* in_sizes, int n_in,
                              void* d_out, int out_size, void* d_ws, size_t ws_size,
                              hipStream_t stream)
{
  const float* x   = (const float*)d_in[0];
  const float* Wq  = (const float*)d_in[1];
  const float* bq  = (const float*)d_in[2];
  const float* Wk  = (const float*)d_in[3];
  const float* bk  = (const float*)d_in[4];
  const float* Wv  = (const float*)d_in[5];
  const float* bv  = (const float*)d_in[6];
  const float* Wo  = (const float*)d_in[7];
  const float* bo  = (const float*)d_in[8];
  const float* W1  = (const float*)d_in[9];
  const float* b1  = (const float*)d_in[10];
  const float* W2  = (const float*)d_in[11];
  const float* b2  = (const float*)d_in[12];
  const float* g1  = (const float*)d_in[13];
  const float* be1 = (const float*)d_in[14];
  const float* g2  = (const float*)d_in[15];
  const float* be2 = (const float*)d_in[16];
  float* out = (float*)d_out;

  char* ws = (char*)d_ws;
  size_t off = 0;
  auto alloc = [&](size_t bytes)->char*{
    char* p = ws + off; off = (off + bytes + 255) & ~(size_t)255; return p;
  };
  bf16*  xb    = (bf16*) alloc((size_t)NTOK*D_*2);
  bf16*  WcatT = (bf16*) alloc((size_t)3*D_*D_*2);
  float* bcat  = (float*)alloc((size_t)3*D_*4);
  bf16*  WoT   = (bf16*) alloc((size_t)D_*D_*2);
  bf16*  W1T   = (bf16*) alloc((size_t)F_*D_*2);
  bf16*  W2T   = (bf16*) alloc((size_t)D_*F_*2);
  bf16*  r1    = (bf16*) alloc((size_t)NTOK*F_*2);     // q,k,vt then ff1
  bf16*  qb    = r1;
  bf16*  kb    = r1 + (size_t)NTOK*D_;
  _Float16* vt = (_Float16*)(r1 + (size_t)2*NTOK*D_);  // [bh*64+d][S], f16, key-permuted
  bf16*  ff1   = r1;
  bf16*  ctxb  = (bf16*) alloc((size_t)NTOK*D_*2);     // ctx then y2
  bf16*  y1    = (bf16*) alloc((size_t)NTOK*D_*2);
  bf16*  hb    = (bf16*) alloc((size_t)NTOK*D_*2);
  bf16*  y2    = ctxb;

  f32_to_bf16_k<<<(NTOK*D_+255)/256, 256, 0, stream>>>(x, xb, NTOK*D_);
  transpose_f32_bf16_k<<<dim3(D_/32, D_/32), 256, 0, stream>>>(Wo, WoT, D_, D_);
  transpose_f32_bf16_k<<<dim3(F_/32, D_/32), 256, 0, stream>>>(W1, W1T, D_, F_);
  transpose_f32_bf16_k<<<dim3(D_/32, F_/32), 256, 0, stream>>>(W2, W2T, F_, D_);
  pack_qkv_t_k<<<(3*D_*D_+255)/256, 256, 0, stream>>>(Wq,bq,Wk,bk,Wv,bv,WcatT,bcat);

  // 1) fused QKV projection (q pre-scaled 1/8; v written transposed+permuted f16)
  mgemm_k<0><<<dim3(3*D_/128, NTOK/128), 256, 0, stream>>>(
      xb, WcatT, bcat, nullptr, nullptr, NTOK, 3*D_, D_, qb, kb, vt);

  // 2) MFMA flash attention -> ctx [8192,768]
  fattn_k<<<dim3(BH_, S_/64), 256, 0, stream>>>(qb, kb, vt, ctxb);

  // 3) out-proj + residual: y1 = ctx@Wo + bo + x   (64x128 tiles, 768 blocks)
  mgemm64_k<<<dim3(D_/128, NTOK/64), 256, 0, stream>>>(
      ctxb, WoT, bo, xb, y1, NTOK, D_, D_);

  // 4) LN1 -> h
  layernorm_k<bf16><<<NTOK, 256, 0, stream>>>(y1, g1, be1, hb);

  // 5) FF1 + fast GELU
  mgemm_k<2><<<dim3(F_/128, NTOK/128), 256, 0, stream>>>(
      hb, W1T, b1, nullptr, ff1, NTOK, F_, D_, nullptr, nullptr, nullptr);

  // 6) FF2 + residual: y2 = ff1@W2 + b2 + h   (64x128 tiles, 768 blocks)
  mgemm64_k<<<dim3(D_/128, NTOK/64), 256, 0, stream>>>(
      ff1, W2T, b2, hb, y2, NTOK, D_, F_);

  // 7) LN2 -> out (fp32)
  layernorm_k<float><<<NTOK, 256, 0, stream>>>(y2, g2, be2, out);
}

// Round 8
// 402.932 us; speedup vs baseline: 1.1488x; 1.0487x over previous
//
#include <hip/hip_runtime.h>
#include <hip/hip_bf16.h>
#include <math.h>

#define B_ 4
#define S_ 2048
#define D_ 768
#define H_ 12
#define DH_ 64
#define F_ 3072
#define NTOK (B_*S_)   // 8192
#define BH_ (B_*H_)    // 48

typedef __hip_bfloat16 bf16;
typedef __attribute__((ext_vector_type(8))) short bf16x8;   // 8 bf16 = 4 VGPRs (MFMA A/B frag)
typedef __attribute__((ext_vector_type(4))) float f32x4;    // MFMA C/D frag
typedef __attribute__((ext_vector_type(4))) _Float16 half4;
typedef __attribute__((ext_vector_type(8))) _Float16 half8;

// async global->LDS: 16 B/lane, lane i lands at ldsbase + i*16 (wave-uniform base)
#define GLD16(g, l) __builtin_amdgcn_global_load_lds( \
    (__attribute__((address_space(1))) void*)(uintptr_t)(g), \
    (__attribute__((address_space(3))) void*)(uintptr_t)(l), 16, 0, 0)

__device__ __forceinline__ float bs2f(short s){
  union { unsigned int u; float f; } cv; cv.u = ((unsigned int)(unsigned short)s) << 16; return cv.f;
}
__device__ __forceinline__ float b2f(bf16 v){ return __bfloat162float(v); }
__device__ __forceinline__ bf16 f2b(float v){ return __float2bfloat16(v); }
__device__ __forceinline__ short f2bb(float v){ bf16 b = f2b(v); short s; __builtin_memcpy(&s, &b, 2); return s; }

// tanh-form GELU rewritten: 0.5x(1+tanh(u)) = x * rcp(1 + exp2(x*(c0 + c1*x^2)))
__device__ __forceinline__ float gelu_fast(float v){
  const float c0 = -2.302208157f;
  const float c1 = -0.102943238f;
  float w = v*v;
  float z = v * __builtin_fmaf(c1, w, c0);
  float t = __builtin_amdgcn_exp2f(z);
  return v * __builtin_amdgcn_rcpf(1.0f + t);
}

// ---------------- fp32 -> bf16 convert ----------------
__global__ void f32_to_bf16_k(const float* __restrict__ in, bf16* __restrict__ out, int n){
  int i = blockIdx.x*256 + threadIdx.x;
  if (i < n) out[i] = f2b(in[i]);
}

// ------- transpose+convert: in[K][N] f32 -> out[N][K] bf16 (LDS 32x32 tiles) -------
__global__ __launch_bounds__(256) void transpose_f32_bf16_k(const float* __restrict__ in,
    bf16* __restrict__ out, int K, int N){
  __shared__ float t[32][33];
  const int kb = blockIdx.y*32, nb = blockIdx.x*32;
  const int x = threadIdx.x & 31, y = threadIdx.x >> 5;
#pragma unroll
  for (int yy = y; yy < 32; yy += 8)
    t[yy][x] = in[(size_t)(kb+yy)*N + nb + x];
  __syncthreads();
#pragma unroll
  for (int yy = y; yy < 32; yy += 8)
    out[(size_t)(nb+yy)*K + kb + x] = f2b(t[x][yy]);
}

// ---- pack Wq/Wk/Wv [H,D,Dh] -> WcatT [3D][D] (n-major, k contiguous), biases -> bcat[3D] ----
__global__ void pack_qkv_t_k(const float* __restrict__ Wq, const float* __restrict__ bq,
                             const float* __restrict__ Wk, const float* __restrict__ bk,
                             const float* __restrict__ Wv, const float* __restrict__ bv,
                             bf16* __restrict__ Wt, float* __restrict__ bcat){
  int idx = blockIdx.x*256 + threadIdx.x;
  if (idx < 3*D_*D_){
    int n = idx / D_;
    int k = idx - n*D_;
    int which = n / D_;
    int cc = n - which*D_;
    int h = cc >> 6, e = cc & 63;
    const float* W = (which==0) ? Wq : ((which==1) ? Wk : Wv);
    Wt[idx] = f2b(W[((size_t)h*D_ + k)*DH_ + e]);
  }
  if (idx < 3*D_){
    int which = idx / D_;
    int cc = idx - which*D_;
    int h = cc >> 6, e = cc & 63;
    const float* bb = (which==0) ? bq : ((which==1) ? bk : bv);
    bcat[idx] = bb[h*DH_ + e];
  }
}

// ---------------- MFMA GEMM 128x128: C[M,N] = A[M,K] @ Bt[N,K]^T ----------------
// BK=32, 4 waves 2x2, global_load_lds width-16 staging, 2-way-only LDS swizzle,
// XCD-aware tile remap. EPI 0: qkv scatter; EPI 2: +bias, fast GELU -> bf16 C
template<int EPI>
__global__ __launch_bounds__(256) void mgemm_k(
    const bf16* __restrict__ A, const bf16* __restrict__ Bt,
    const float* __restrict__ bias, const bf16* __restrict__ aux,
    bf16* __restrict__ C, int M, int N, int K,
    bf16* __restrict__ qb, bf16* __restrict__ kbuf, _Float16* __restrict__ vt)
{
  __shared__ bf16 As[4096];   // [128][32] unpadded, 8 KB
  __shared__ bf16 Bs[4096];
  const int tid  = threadIdx.x;
  const int wave = tid >> 6, lane = tid & 63;
  const int quad = lane >> 4, l16 = lane & 15;
  const int wm = (wave >> 1) * 64, wn = (wave & 1) * 64;

  // XCD-aware remap (gridDim.y % 8 == 0 for all our launches)
  const int NX = gridDim.x;
  const int f  = blockIdx.y * NX + blockIdx.x;
  const int xcd = f & 7;
  const int j   = f >> 3;
  const int bx  = j % NX;
  const int by  = (j / NX) * 8 + xcd;
  const int m0 = by * 128, n0 = bx * 128;

  // staging: lane covers row wave*16 + (lane>>2), swizzled chunk ((lane&3)^((srow>>1)&3))
  const int srow  = lane >> 2;
  const int schunk = (lane & 3) ^ ((srow >> 1) & 3);
  const bf16* gA0 = A  + (size_t)(m0 + wave*16 + srow)*K + schunk*8;
  const bf16* gA1 = gA0 + (size_t)64*K;
  const bf16* gB0 = Bt + (size_t)(n0 + wave*16 + srow)*K + schunk*8;
  const bf16* gB1 = gB0 + (size_t)64*K;
  const uintptr_t asb = (uintptr_t)(void*)As + (size_t)wave*1024;
  const uintptr_t bsb = (uintptr_t)(void*)Bs + (size_t)wave*1024;

  f32x4 acc[4][4];
#pragma unroll
  for (int i=0;i<4;i++)
#pragma unroll
    for (int j2=0;j2<4;j2++) acc[i][j2] = (f32x4)0.f;

  const char* AsB = (const char*)As;
  const char* BsB = (const char*)Bs;
  const int fsw = (quad ^ ((l16 >> 1) & 3)) * 16;   // frag-read swizzled chunk byte offset

  for (int k0 = 0; k0 < K; k0 += 32){
    __syncthreads();                      // prior frag reads done before overwrite
    GLD16(gA0, asb);
    GLD16(gA1, asb + 4096);
    GLD16(gB0, bsb);
    GLD16(gB1, bsb + 4096);
    gA0 += 32; gA1 += 32; gB0 += 32; gB1 += 32;
    __syncthreads();                      // drains vmcnt -> LDS visible
    bf16x8 af[4], bfr[4];
#pragma unroll
    for (int i=0;i<4;i++) af[i]  = *(const bf16x8*)(AsB + ((wm + i*16 + l16) << 6) + fsw);
#pragma unroll
    for (int j2=0;j2<4;j2++) bfr[j2] = *(const bf16x8*)(BsB + ((wn + j2*16 + l16) << 6) + fsw);
#pragma unroll
    for (int i=0;i<4;i++)
#pragma unroll
      for (int j2=0;j2<4;j2++)
        acc[i][j2] = __builtin_amdgcn_mfma_f32_16x16x32_bf16(af[i], bfr[j2], acc[i][j2], 0, 0, 0);
  }

#pragma unroll
  for (int i=0;i<4;i++){
#pragma unroll
    for (int j2=0;j2<4;j2++){
      const int n = n0 + wn + j2*16 + l16;
      const int m_base = m0 + wm + i*16 + quad*4;
      if (EPI == 0){
        const int which = n / D_;
        const int cc = n - which*D_;
        const int h = cc >> 6, e = cc & 63;
        if (which == 2){
          const int b = m_base >> 11, s = m_base & (S_-1);
          const int sl = s & 63;
          const int perm = ((sl>>2)&3)*16 + ((sl>>4)&3)*4;   // key-permuted V^T layout
          half4 hv;
#pragma unroll
          for (int r=0;r<4;r++) hv[r] = (_Float16)(acc[i][j2][r] + bias[n]);
          *(half4*)(vt + ((size_t)(b*H_+h)*DH_ + e)*S_ + (s & ~63) + perm) = hv;
        } else {
          bf16* dst = (which==0) ? qb : kbuf;
          const float sc2 = (which==0) ? 0.125f : 1.0f;   // fold softmax 1/sqrt(64) into q
#pragma unroll
          for (int r=0;r<4;r++){
            const int m = m_base + r;
            const int b = m >> 11, s = m & (S_-1);
            dst[((size_t)(b*H_+h)*S_ + s)*DH_ + e] = f2b((acc[i][j2][r] + bias[n]) * sc2);
          }
        }
      } else {
#pragma unroll
        for (int r=0;r<4;r++){
          const int m = m_base + r;
          float v = acc[i][j2][r] + bias[n];
          if (EPI == 1){
            v += b2f(aux[(size_t)m*N + n]);
            C[(size_t)m*N + n] = f2b(v);
          } else {
            C[(size_t)m*N + n] = f2b(gelu_fast(v));
          }
        }
      }
    }
  }
}

// ---------------- MFMA GEMM 64x128, BK=64 (for N=768 GEMMs: proj, FF2) ----------------
// TM=64, TN=128, BK=64: half the barrier drains of BK=32 at the same staged bytes.
// LDS rows are 128 B (64 bf16); swizzle: slot c of row r holds global chunk c ^ (r&7)
// -> per-quad-phase 2-way bank aliasing (free). Grid (N/128, M/64). EPI1:
// C = A@Bt^T + bias + aux (residual), bf16 out.
__global__ __launch_bounds__(256) void mgemm64_k(
    const bf16* __restrict__ A, const bf16* __restrict__ Bt,
    const float* __restrict__ bias, const bf16* __restrict__ aux,
    bf16* __restrict__ C, int M, int N, int K)
{
  __shared__ bf16 As[4096];   // [64][64]  8 KB
  __shared__ bf16 Bs[8192];   // [128][64] 16 KB
  const int tid  = threadIdx.x;
  const int wave = tid >> 6, lane = tid & 63;
  const int quad = lane >> 4, l16 = lane & 15;
  const int wm = (wave >> 1) * 32, wn = (wave & 1) * 64;

  const int NX = gridDim.x;
  const int f  = blockIdx.y * NX + blockIdx.x;
  const int xcd = f & 7;
  const int j   = f >> 3;
  const int bx  = j % NX;
  const int by  = (j / NX) * 8 + xcd;
  const int m0 = by * 64, n0 = bx * 128;

  // staging: one GLD16 covers 8 rows of 128 B. lane -> row (lane>>3), slot (lane&7),
  // global chunk g = slot ^ (row&7)  (row offsets are multiples of 8, so g is lane-only)
  const int srow8 = lane >> 3;                       // 0..7
  const int g     = (lane & 7) ^ srow8;              // global 16B-chunk within the row
  // A: wave stages rows wave*16 + t*8 (t=0,1);  B: rows wave*32 + t*8 (t=0..3)
  const bf16* gA0 = A  + (size_t)(m0 + wave*16 +      srow8)*K + g*8;
  const bf16* gA1 = A  + (size_t)(m0 + wave*16 +  8 + srow8)*K + g*8;
  const bf16* gB0 = Bt + (size_t)(n0 + wave*32 +      srow8)*K + g*8;
  const bf16* gB1 = Bt + (size_t)(n0 + wave*32 +  8 + srow8)*K + g*8;
  const bf16* gB2 = Bt + (size_t)(n0 + wave*32 + 16 + srow8)*K + g*8;
  const bf16* gB3 = Bt + (size_t)(n0 + wave*32 + 24 + srow8)*K + g*8;
  const uintptr_t asb = (uintptr_t)(void*)As + (size_t)wave*16*128;
  const uintptr_t bsb = (uintptr_t)(void*)Bs + (size_t)wave*32*128;

  f32x4 acc[2][4];
#pragma unroll
  for (int i=0;i<2;i++)
#pragma unroll
    for (int j2=0;j2<4;j2++) acc[i][j2] = (f32x4)0.f;

  const char* AsB = (const char*)As;
  const char* BsB = (const char*)Bs;

  for (int k0 = 0; k0 < K; k0 += 64){
    __syncthreads();
    GLD16(gA0, asb);
    GLD16(gA1, asb + 1024);
    GLD16(gB0, bsb);
    GLD16(gB1, bsb + 1024);
    GLD16(gB2, bsb + 2048);
    GLD16(gB3, bsb + 3072);
    gA0 += 64; gA1 += 64; gB0 += 64; gB1 += 64; gB2 += 64; gB3 += 64;
    __syncthreads();
#pragma unroll
    for (int kq = 0; kq < 2; kq++){
      const int cbase = kq*4 + quad;
      bf16x8 af[2], bfr[4];
#pragma unroll
      for (int i=0;i<2;i++){
        const int m = wm + i*16 + l16;
        af[i] = *(const bf16x8*)(AsB + (m << 7) + ((cbase ^ (m & 7)) << 4));
      }
#pragma unroll
      for (int j2=0;j2<4;j2++){
        const int n = wn + j2*16 + l16;
        bfr[j2] = *(const bf16x8*)(BsB + (n << 7) + ((cbase ^ (n & 7)) << 4));
      }
#pragma unroll
      for (int i=0;i<2;i++)
#pragma unroll
        for (int j2=0;j2<4;j2++)
          acc[i][j2] = __builtin_amdgcn_mfma_f32_16x16x32_bf16(af[i], bfr[j2], acc[i][j2], 0, 0, 0);
    }
  }

#pragma unroll
  for (int i=0;i<2;i++){
#pragma unroll
    for (int j2=0;j2<4;j2++){
      const int n = n0 + wn + j2*16 + l16;
      const int m_base = m0 + wm + i*16 + quad*4;
#pragma unroll
      for (int r=0;r<4;r++){
        const int m = m_base + r;
        float v = acc[i][j2][r] + bias[n] + b2f(aux[(size_t)m*N + n]);
        C[(size_t)m*N + n] = f2b(v);
      }
    }
  }
}

// ---------------- MFMA flash attention ----------------
__global__ __launch_bounds__(256) void fattn_k(const bf16* __restrict__ qb,
    const bf16* __restrict__ kb, const _Float16* __restrict__ vt, bf16* __restrict__ ctx)
{
  __shared__ __align__(16) char smem[19456];
  bf16     (*Ks)[72] = (bf16(*)[72])smem;                  // [64 keys][72] bf16
  _Float16 (*Vs)[72] = (_Float16(*)[72])(smem + 9216);     // [64 d][72 keys(permuted)] f16
  float* maxb  = (float*)(smem + 18432);                   // [2 kh][64 q]
  float* libuf = (float*)(smem + 18944);                   // [2 kh][64 q]
  float* Obuf  = (float*)smem;                             // alias (end)

  const int bh = blockIdx.x;
  const int qt = 31 - blockIdx.y;       // heavy tiles first
  const int q0 = qt * 64;
  const int tid = threadIdx.x;
  const int wave = tid >> 6, lane = tid & 63;
  const int quad = lane >> 4, l16 = lane & 15;
  const int kh = wave >> 1, qh = wave & 1;
  const size_t kbase = (size_t)bh * S_ * DH_;

  bf16x8 qf[2][2];
#pragma unroll
  for (int nf=0; nf<2; nf++)
#pragma unroll
    for (int h=0; h<2; h++)
      qf[nf][h] = *(const bf16x8*)(qb + kbase + (size_t)(q0 + qh*32 + nf*16 + l16)*DH_ + h*32 + quad*8);

  f32x4 o[4][2];
#pragma unroll
  for (int df=0; df<4; df++){ o[df][0] = (f32x4)0.f; o[df][1] = (f32x4)0.f; }
  float mi[2] = {-1e30f, -1e30f}, li[2] = {0.f, 0.f};

  for (int kt = 0; kt <= qt; ++kt){
    const int k0 = kt * 64;
    __syncthreads();
    { // stage K (natural) and V^T (permuted keys)
      const int r = tid >> 2, seg = (tid & 3) * 16;
      const bf16* ksrc = kb + kbase + (size_t)(k0 + r)*DH_ + seg;
      bf16x8 ka = *(const bf16x8*)ksrc;
      bf16x8 kc2 = *(const bf16x8*)(ksrc + 8);
      *(bf16x8*)&Ks[r][seg]   = ka;
      *(bf16x8*)&Ks[r][seg+8] = kc2;
      const _Float16* vsrc = vt + ((size_t)bh*DH_ + r)*S_ + k0 + seg;
      half8 va = *(const half8*)vsrc;
      half8 vb2 = *(const half8*)(vsrc + 8);
      *(half8*)&Vs[r][seg]   = va;
      *(half8*)&Vs[r][seg+8] = vb2;
    }
    __syncthreads();

    bf16x8 af[2][2];
#pragma unroll
    for (int mf=0; mf<2; mf++)
#pragma unroll
      for (int h=0; h<2; h++)
        af[mf][h] = *(const bf16x8*)&Ks[kh*32 + mf*16 + l16][h*32 + quad*8];
    f32x4 sc[2][2];
#pragma unroll
    for (int mf=0; mf<2; mf++)
#pragma unroll
      for (int nf=0; nf<2; nf++){
        f32x4 t = __builtin_amdgcn_mfma_f32_16x16x32_bf16(af[mf][0], qf[nf][0], (f32x4)0.f, 0, 0, 0);
        sc[mf][nf] = __builtin_amdgcn_mfma_f32_16x16x32_bf16(af[mf][1], qf[nf][1], t, 0, 0, 0);
      }

    if (kt == qt){
#pragma unroll
      for (int mf=0; mf<2; mf++){
        const int keyl = kh*32 + mf*16 + quad*4;
#pragma unroll
        for (int nf=0; nf<2; nf++){
          const int ql = qh*32 + nf*16 + l16;
#pragma unroll
          for (int r=0; r<4; r++)
            if (keyl + r > ql) sc[mf][nf][r] = -1e30f;
        }
      }
    }

    float mw[2];
#pragma unroll
    for (int nf=0; nf<2; nf++){
      float mx = -1e30f;
#pragma unroll
      for (int mf=0; mf<2; mf++)
#pragma unroll
        for (int r=0; r<4; r++) mx = fmaxf(mx, sc[mf][nf][r]);
      mx = fmaxf(mx, __shfl_xor(mx, 16));
      mx = fmaxf(mx, __shfl_xor(mx, 32));
      mw[nf] = mx;
    }
    if (quad == 0){
      maxb[kh*64 + qh*32 + l16]      = mw[0];
      maxb[kh*64 + qh*32 + 16 + l16] = mw[1];
    }
    __syncthreads();

    half4 pf[2][2];
    float alpha[2];
#pragma unroll
    for (int nf=0; nf<2; nf++){
      const float mo = maxb[(1-kh)*64 + qh*32 + nf*16 + l16];
      const float mn = fmaxf(mi[nf], fmaxf(mw[nf], mo));
      alpha[nf] = __expf(mi[nf] - mn);
      mi[nf] = mn;
      float rs = 0.f;
#pragma unroll
      for (int mf=0; mf<2; mf++)
#pragma unroll
        for (int r=0; r<4; r++){
          float p = __expf(sc[mf][nf][r] - mn);
          pf[mf][nf][r] = (_Float16)p;
          rs += p;
        }
      rs += __shfl_xor(rs, 16);
      rs += __shfl_xor(rs, 32);
      li[nf] = li[nf]*alpha[nf] + rs;
    }

#pragma unroll
    for (int df=0; df<4; df++)
#pragma unroll
      for (int nf=0; nf<2; nf++)
#pragma unroll
        for (int r=0; r<4; r++) o[df][nf][r] *= alpha[nf];

#pragma unroll
    for (int df=0; df<4; df++){
      half8 vv = *(const half8*)&Vs[df*16 + l16][quad*16 + kh*8];
      half4 vlo = __builtin_shufflevector(vv, vv, 0,1,2,3);
      half4 vhi = __builtin_shufflevector(vv, vv, 4,5,6,7);
#pragma unroll
      for (int nf=0; nf<2; nf++){
        o[df][nf] = __builtin_amdgcn_mfma_f32_16x16x16f16(vlo, pf[0][nf], o[df][nf], 0, 0, 0);
        o[df][nf] = __builtin_amdgcn_mfma_f32_16x16x16f16(vhi, pf[1][nf], o[df][nf], 0, 0, 0);
      }
    }
  }

  __syncthreads();
  if (quad == 0){
    libuf[kh*64 + qh*32 + l16]      = li[0];
    libuf[kh*64 + qh*32 + 16 + l16] = li[1];
  }
  if (kh == 1){
#pragma unroll
    for (int df=0; df<4; df++)
#pragma unroll
      for (int nf=0; nf<2; nf++)
#pragma unroll
        for (int r=0; r<4; r++)
          Obuf[(qh*64 + df*16 + quad*4 + r)*33 + nf*16 + l16] = o[df][nf][r];
  }
  __syncthreads();
  if (kh == 0){
    const int b = bh / H_, h = bh - (bh / H_)*H_;
#pragma unroll
    for (int nf=0; nf<2; nf++){
      const int q64 = qh*32 + nf*16 + l16;
      const float inv = 1.0f / (libuf[q64] + libuf[64 + q64]);
      const int qtok = q0 + q64;
#pragma unroll
      for (int df=0; df<4; df++){
        short4 pk;
        float v0 = (o[df][nf][0] + Obuf[(qh*64 + df*16 + quad*4 + 0)*33 + nf*16 + l16]) * inv;
        float v1 = (o[df][nf][1] + Obuf[(qh*64 + df*16 + quad*4 + 1)*33 + nf*16 + l16]) * inv;
        float v2 = (o[df][nf][2] + Obuf[(qh*64 + df*16 + quad*4 + 2)*33 + nf*16 + l16]) * inv;
        float v3 = (o[df][nf][3] + Obuf[(qh*64 + df*16 + quad*4 + 3)*33 + nf*16 + l16]) * inv;
        pk.x = f2bb(v0); pk.y = f2bb(v1); pk.z = f2bb(v2); pk.w = f2bb(v3);
        *(short4*)((short*)ctx + ((size_t)(b*S_ + qtok))*D_ + h*DH_ + df*16 + quad*4) = pk;
      }
    }
  }
}

// ---------------- layernorm over D=768 ----------------
template<typename T> __device__ __forceinline__ void stf(T* p, float v);
template<> __device__ __forceinline__ void stf<float>(float* p, float v){ *p = v; }
template<> __device__ __forceinline__ void stf<bf16>(bf16* p, float v){ *p = f2b(v); }

template<typename OutT>
__global__ __launch_bounds__(256) void layernorm_k(const bf16* __restrict__ X,
    const float* __restrict__ g, const float* __restrict__ bta, OutT* __restrict__ Y)
{
  const int row = blockIdx.x;
  const int tid = threadIdx.x;
  const bf16* xr = X + (size_t)row * D_;
  float vals[3];
  float s = 0.f, s2 = 0.f;
#pragma unroll
  for (int i = 0; i < 3; i++){
    float v = b2f(xr[tid + i*256]);
    vals[i] = v; s += v; s2 += v*v;
  }
#pragma unroll
  for (int o = 32; o > 0; o >>= 1){ s += __shfl_down(s, o); s2 += __shfl_down(s2, o); }
  __shared__ float rs[4], rq[4];
  const int lane = tid & 63, w = tid >> 6;
  if (lane == 0){ rs[w] = s; rq[w] = s2; }
  __syncthreads();
  s  = rs[0]+rs[1]+rs[2]+rs[3];
  s2 = rq[0]+rq[1]+rq[2]+rq[3];
  const float mean = s * (1.0f/D_);
  const float var  = s2 * (1.0f/D_) - mean*mean;
  const float inv  = rsqrtf(var + 1e-5f);
#pragma unroll
  for (int i = 0; i < 3; i++){
    int c = tid + i*256;
    float o = (vals[i] - mean) * inv * g[c] + bta[c];
    stf(Y + (size_t)row*D_ + c, o);
  }
}

extern "C" void kernel_launch(void* const* d_in, const int* in_sizes, int n_in,
                              void* d_out, int out_size, void* d_ws, size_t ws_size,
                              hipStream_t stream)
{
  const float* x   = (const float*)d_in[0];
  const float* Wq  = (const float*)d_in[1];
  const float* bq  = (const float*)d_in[2];
  const float* Wk  = (const float*)d_in[3];
  const float* bk  = (const float*)d_in[4];
  const float* Wv  = (const float*)d_in[5];
  const float* bv  = (const float*)d_in[6];
  const float* Wo  = (const float*)d_in[7];
  const float* bo  = (const float*)d_in[8];
  const float* W1  = (const float*)d_in[9];
  const float* b1  = (const float*)d_in[10];
  const float* W2  = (const float*)d_in[11];
  const float* b2  = (const float*)d_in[12];
  const float* g1  = (const float*)d_in[13];
  const float* be1 = (const float*)d_in[14];
  const float* g2  = (const float*)d_in[15];
  const float* be2 = (const float*)d_in[16];
  float* out = (float*)d_out;

  char* ws = (char*)d_ws;
  size_t off = 0;
  auto alloc = [&](size_t bytes)->char*{
    char* p = ws + off; off = (off + bytes + 255) & ~(size_t)255; return p;
  };
  bf16*  xb    = (bf16*) alloc((size_t)NTOK*D_*2);
  bf16*  WcatT = (bf16*) alloc((size_t)3*D_*D_*2);
  float* bcat  = (float*)alloc((size_t)3*D_*4);
  bf16*  WoT   = (bf16*) alloc((size_t)D_*D_*2);
  bf16*  W1T   = (bf16*) alloc((size_t)F_*D_*2);
  bf16*  W2T   = (bf16*) alloc((size_t)D_*F_*2);
  bf16*  r1    = (bf16*) alloc((size_t)NTOK*F_*2);     // q,k,vt then ff1
  bf16*  qb    = r1;
  bf16*  kb    = r1 + (size_t)NTOK*D_;
  _Float16* vt = (_Float16*)(r1 + (size_t)2*NTOK*D_);  // [bh*64+d][S], f16, key-permuted
  bf16*  ff1   = r1;
  bf16*  ctxb  = (bf16*) alloc((size_t)NTOK*D_*2);     // ctx then y2
  bf16*  y1    = (bf16*) alloc((size_t)NTOK*D_*2);
  bf16*  hb    = (bf16*) alloc((size_t)NTOK*D_*2);
  bf16*  y2    = ctxb;

  f32_to_bf16_k<<<(NTOK*D_+255)/256, 256, 0, stream>>>(x, xb, NTOK*D_);
  transpose_f32_bf16_k<<<dim3(D_/32, D_/32), 256, 0, stream>>>(Wo, WoT, D_, D_);
  transpose_f32_bf16_k<<<dim3(F_/32, D_/32), 256, 0, stream>>>(W1, W1T, D_, F_);
  transpose_f32_bf16_k<<<dim3(D_/32, F_/32), 256, 0, stream>>>(W2, W2T, F_, D_);
  pack_qkv_t_k<<<(3*D_*D_+255)/256, 256, 0, stream>>>(Wq,bq,Wk,bk,Wv,bv,WcatT,bcat);

  // 1) fused QKV projection (q pre-scaled 1/8; v written transposed+permuted f16)
  mgemm_k<0><<<dim3(3*D_/128, NTOK/128), 256, 0, stream>>>(
      xb, WcatT, bcat, nullptr, nullptr, NTOK, 3*D_, D_, qb, kb, vt);

  // 2) MFMA flash attention -> ctx [8192,768]
  fattn_k<<<dim3(BH_, S_/64), 256, 0, stream>>>(qb, kb, vt, ctxb);

  // 3) out-proj + residual: y1 = ctx@Wo + bo + x   (64x128 tiles, BK=64)
  mgemm64_k<<<dim3(D_/128, NTOK/64), 256, 0, stream>>>(
      ctxb, WoT, bo, xb, y1, NTOK, D_, D_);

  // 4) LN1 -> h
  layernorm_k<bf16><<<NTOK, 256, 0, stream>>>(y1, g1, be1, hb);

  // 5) FF1 + fast GELU
  mgemm_k<2><<<dim3(F_/128, NTOK/128), 256, 0, stream>>>(
      hb, W1T, b1, nullptr, ff1, NTOK, F_, D_, nullptr, nullptr, nullptr);

  // 6) FF2 + residual: y2 = ff1@W2 + b2 + h   (64x128 tiles, BK=64)
  mgemm64_k<<<dim3(D_/128, NTOK/64), 256, 0, stream>>>(
      ff1, W2T, b2, hb, y2, NTOK, D_, F_);

  // 7) LN2 -> out (fp32)
  layernorm_k<float><<<NTOK, 256, 0, stream>>>(y2, g2, be2, out);
}